// Round 9
// baseline (396.866 us; speedup 1.0000x reference)
//
#include <hip/hip_runtime.h>
#include <hip/hip_bf16.h>

// x (B=256, R=1024, C=1024) fp32; rows/cols: 64 int32 indices each.
// out = x, except at (b, rows[i], cols[j]) apply mute_msb:
//   if biased exponent E in [127,255) (|x|>=1, finite): set exponent to 126
//   (x -> signed mantissa in [0.5,1)); else identity.
//
// R9 single-variable A/B vs R8: plain (cached) loads instead of nontemporal
// loads; stores stay nontemporal. Everything else identical to R8:
//  - per-block LDS bitmask build (fused, parallel)
//  - ping-pong A/B register buffers
//  - rowstride % R == 0 -> row membership hoisted out of the loop

#define RR 1024
#define CC 1024
#define UNROLL 4

typedef float f4 __attribute__((ext_vector_type(4)));

__device__ __forceinline__ void mute4(f4& v, unsigned m) {
#pragma unroll
    for (int k = 0; k < 4; ++k) {
        if ((m >> k) & 1u) {
            unsigned u = __float_as_uint(v[k]);
            unsigned E = (u >> 23) & 0xffu;
            if (E >= 127u && E < 255u)
                v[k] = __uint_as_float((u & 0x807fffffu) | (126u << 23));
        }
    }
}

#define LOADV(V, qq)                                                        \
    _Pragma("unroll") for (int k = 0; k < UNROLL; ++k)                      \
        V[k] = x[(qq) + k * 256];

#define PSTOREV(V, qq)                                                      \
    _Pragma("unroll") for (int k = 0; k < UNROLL; ++k) {                    \
        f4 t = V[k];                                                        \
        if (rb[k]) mute4(t, colnib);                                        \
        __builtin_nontemporal_store(t, &out[(qq) + k * 256]);               \
    }

__global__ void __launch_bounds__(256)
copy_mute_kernel(const f4* __restrict__ x,
                 f4* __restrict__ out,
                 const int* __restrict__ rows,
                 const int* __restrict__ cols,
                 int nr, int nc, int nrows) {          // nrows = B * R
    // Per-block mask build: smask[0..31] row bits, smask[32..63] col bits.
    __shared__ unsigned smask[64];
    int tid = threadIdx.x;
    if (tid < 64) smask[tid] = 0u;
    __syncthreads();
    if (tid < nr) {
        int r = rows[tid];
        atomicOr(&smask[r >> 5], 1u << (r & 31));
    } else if (tid >= 64 && tid < 64 + nc) {
        int c = cols[tid - 64];
        atomicOr(&smask[32 + (c >> 5)], 1u << (c & 31));
    }
    __syncthreads();

    // This lane always handles columns [tid*4, tid*4+4): nibble invariant.
    unsigned colword = smask[32 + (tid >> 3)];
    unsigned colnib = (colword >> ((tid & 7) * 4)) & 0xFu;

    int row0 = blockIdx.x * UNROLL;
    if (row0 >= nrows) return;
    int rowstride = gridDim.x * UNROLL;               // host guarantees % RR == 0 (or iters==1)
    long long qstride = (long long)rowstride * 256;

    // Loop-invariant row membership (row mod RR constant across iterations).
    bool rb[UNROLL];
#pragma unroll
    for (int k = 0; k < UNROLL; ++k) {
        int r = (row0 + k) & (RR - 1);
        rb[k] = ((smask[r >> 5] >> (r & 31)) & 1u) != 0u;
    }

    int iters = (nrows - row0 + rowstride - 1) / rowstride;
    long long q0 = (long long)row0 * 256 + tid;

    f4 A[UNROLL], B[UNROLL];
    LOADV(A, q0)
    long long qprev = q0;
    bool prevA = true;
    for (int t = 1; t < iters; ++t) {
        long long qt = qprev + qstride;
        if (prevA) { LOADV(B, qt) PSTOREV(A, qprev) }
        else       { LOADV(A, qt) PSTOREV(B, qprev) }
        prevA = !prevA;
        qprev = qt;
    }
    if (prevA) { PSTOREV(A, qprev) }
    else       { PSTOREV(B, qprev) }
}

extern "C" void kernel_launch(void* const* d_in, const int* in_sizes, int n_in,
                              void* d_out, int out_size, void* d_ws, size_t ws_size,
                              hipStream_t stream) {
    const float* x  = (const float*)d_in[0];
    const int* rows = (const int*)d_in[1];
    const int* cols = (const int*)d_in[2];
    float* out      = (float*)d_out;

    const int nr = in_sizes[1];
    const int nc = in_sizes[2];

    int nrows = in_sizes[0] / CC;   // B * R = 262144
    int block = 256;
    int grid = 4096;                // 4096*4 = 16384 rows/sweep, % 1024 == 0
    if (grid * UNROLL > nrows) grid = (nrows + UNROLL - 1) / UNROLL;  // -> iters==1
    copy_mute_kernel<<<grid, block, 0, stream>>>(
        (const f4*)x, (f4*)out, rows, cols, nr, nc, nrows);
}

// Round 10
// 379.603 us; speedup vs baseline: 1.0455x; 1.0455x over previous
//
#include <hip/hip_runtime.h>
#include <hip/hip_bf16.h>

// x (B=256, R=1024, C=1024) fp32; rows/cols: 64 int32 indices each.
// out = x, except at (b, rows[i], cols[j]) apply mute_msb:
//   if biased exponent E in [127,255) (|x|>=1, finite): set exponent to 126
//   (x -> signed mantissa in [0.5,1)); else identity.
//
// R10 single-variable A/B vs R8: pipeline depth 4 -> 8 (ping-pong, no shift
// copies). All else identical to R8: full nontemporal load+store, fused
// per-block LDS mask build, hoisted row membership. grid=2048 so the device
// is exactly fully resident and rowstride (2048*8=16384) % 1024 == 0.

#define RR 1024
#define CC 1024
#define UNROLL 8

typedef float f4 __attribute__((ext_vector_type(4)));

__device__ __forceinline__ void mute4(f4& v, unsigned m) {
#pragma unroll
    for (int k = 0; k < 4; ++k) {
        if ((m >> k) & 1u) {
            unsigned u = __float_as_uint(v[k]);
            unsigned E = (u >> 23) & 0xffu;
            if (E >= 127u && E < 255u)
                v[k] = __uint_as_float((u & 0x807fffffu) | (126u << 23));
        }
    }
}

#define LOADV(V, qq)                                                        \
    _Pragma("unroll") for (int k = 0; k < UNROLL; ++k)                      \
        V[k] = __builtin_nontemporal_load(&x[(qq) + k * 256]);

#define PSTOREV(V, qq)                                                      \
    _Pragma("unroll") for (int k = 0; k < UNROLL; ++k) {                    \
        f4 t = V[k];                                                        \
        if (rb[k]) mute4(t, colnib);                                        \
        __builtin_nontemporal_store(t, &out[(qq) + k * 256]);               \
    }

__global__ void __launch_bounds__(256)
copy_mute_kernel(const f4* __restrict__ x,
                 f4* __restrict__ out,
                 const int* __restrict__ rows,
                 const int* __restrict__ cols,
                 int nr, int nc, int nrows) {          // nrows = B * R
    // Per-block mask build: smask[0..31] row bits, smask[32..63] col bits.
    __shared__ unsigned smask[64];
    int tid = threadIdx.x;
    if (tid < 64) smask[tid] = 0u;
    __syncthreads();
    if (tid < nr) {
        int r = rows[tid];
        atomicOr(&smask[r >> 5], 1u << (r & 31));
    } else if (tid >= 64 && tid < 64 + nc) {
        int c = cols[tid - 64];
        atomicOr(&smask[32 + (c >> 5)], 1u << (c & 31));
    }
    __syncthreads();

    // This lane always handles columns [tid*4, tid*4+4): nibble invariant.
    unsigned colword = smask[32 + (tid >> 3)];
    unsigned colnib = (colword >> ((tid & 7) * 4)) & 0xFu;

    int row0 = blockIdx.x * UNROLL;
    if (row0 >= nrows) return;
    int rowstride = gridDim.x * UNROLL;               // host guarantees % RR == 0 (or iters==1)
    long long qstride = (long long)rowstride * 256;

    // Loop-invariant row membership (row mod RR constant across iterations).
    bool rb[UNROLL];
#pragma unroll
    for (int k = 0; k < UNROLL; ++k) {
        int r = (row0 + k) & (RR - 1);
        rb[k] = ((smask[r >> 5] >> (r & 31)) & 1u) != 0u;
    }

    int iters = (nrows - row0 + rowstride - 1) / rowstride;
    long long q0 = (long long)row0 * 256 + tid;

    f4 A[UNROLL], B[UNROLL];
    LOADV(A, q0)
    long long qprev = q0;
    bool prevA = true;
    for (int t = 1; t < iters; ++t) {
        long long qt = qprev + qstride;
        if (prevA) { LOADV(B, qt) PSTOREV(A, qprev) }
        else       { LOADV(A, qt) PSTOREV(B, qprev) }
        prevA = !prevA;
        qprev = qt;
    }
    if (prevA) { PSTOREV(A, qprev) }
    else       { PSTOREV(B, qprev) }
}

extern "C" void kernel_launch(void* const* d_in, const int* in_sizes, int n_in,
                              void* d_out, int out_size, void* d_ws, size_t ws_size,
                              hipStream_t stream) {
    const float* x  = (const float*)d_in[0];
    const int* rows = (const int*)d_in[1];
    const int* cols = (const int*)d_in[2];
    float* out      = (float*)d_out;

    const int nr = in_sizes[1];
    const int nc = in_sizes[2];

    int nrows = in_sizes[0] / CC;   // B * R = 262144
    int block = 256;
    int grid = 2048;                // 2048*8 = 16384 rows/sweep, % 1024 == 0
    if (grid * UNROLL > nrows) grid = (nrows + UNROLL - 1) / UNROLL;  // -> iters==1
    copy_mute_kernel<<<grid, block, 0, stream>>>(
        (const f4*)x, (f4*)out, rows, cols, nr, nc, nrows);
}

// Round 11
// 371.114 us; speedup vs baseline: 1.0694x; 1.0229x over previous
//
#include <hip/hip_runtime.h>
#include <hip/hip_bf16.h>

// x (B=256, R=1024, C=1024) fp32; rows/cols: 64 int32 indices each.
// out = x, except at (b, rows[i], cols[j]) apply mute_msb:
//   if biased exponent E in [127,255) (|x|>=1, finite): set exponent to 126
//   (x -> signed mantissa in [0.5,1)); else identity.
//
// FINAL (= R8, the best measured configuration: 372 µs, 5.77 TB/s, 91.7% of
// the float4-copy µbench ceiling). Ladder of verified A/Bs:
//  - minimal traffic 2.15 GB (FETCH+WRITE confirm)
//  - nontemporal loads AND stores (+7% vs cached loads, R9 A/B)
//  - ping-pong A/B register buffers, depth 4 (depth 8 regresses, R10 A/B)
//  - rowstride % R == 0 -> row membership + mute nibble hoisted out of loop
//  - per-block LDS mask build fused into the copy kernel (one dispatch)

#define RR 1024
#define CC 1024
#define UNROLL 4

typedef float f4 __attribute__((ext_vector_type(4)));

__device__ __forceinline__ void mute4(f4& v, unsigned m) {
#pragma unroll
    for (int k = 0; k < 4; ++k) {
        if ((m >> k) & 1u) {
            unsigned u = __float_as_uint(v[k]);
            unsigned E = (u >> 23) & 0xffu;
            if (E >= 127u && E < 255u)
                v[k] = __uint_as_float((u & 0x807fffffu) | (126u << 23));
        }
    }
}

#define LOADV(V, qq)                                                        \
    _Pragma("unroll") for (int k = 0; k < UNROLL; ++k)                      \
        V[k] = __builtin_nontemporal_load(&x[(qq) + k * 256]);

#define PSTOREV(V, qq)                                                      \
    _Pragma("unroll") for (int k = 0; k < UNROLL; ++k) {                    \
        f4 t = V[k];                                                        \
        if (rb[k]) mute4(t, colnib);                                        \
        __builtin_nontemporal_store(t, &out[(qq) + k * 256]);               \
    }

__global__ void __launch_bounds__(256)
copy_mute_kernel(const f4* __restrict__ x,
                 f4* __restrict__ out,
                 const int* __restrict__ rows,
                 const int* __restrict__ cols,
                 int nr, int nc, int nrows) {          // nrows = B * R
    // Per-block mask build: smask[0..31] row bits, smask[32..63] col bits.
    __shared__ unsigned smask[64];
    int tid = threadIdx.x;
    if (tid < 64) smask[tid] = 0u;
    __syncthreads();
    if (tid < nr) {
        int r = rows[tid];
        atomicOr(&smask[r >> 5], 1u << (r & 31));
    } else if (tid >= 64 && tid < 64 + nc) {
        int c = cols[tid - 64];
        atomicOr(&smask[32 + (c >> 5)], 1u << (c & 31));
    }
    __syncthreads();

    // This lane always handles columns [tid*4, tid*4+4): nibble invariant.
    unsigned colword = smask[32 + (tid >> 3)];
    unsigned colnib = (colword >> ((tid & 7) * 4)) & 0xFu;

    int row0 = blockIdx.x * UNROLL;
    if (row0 >= nrows) return;
    int rowstride = gridDim.x * UNROLL;               // host guarantees % RR == 0 (or iters==1)
    long long qstride = (long long)rowstride * 256;

    // Loop-invariant row membership (row mod RR constant across iterations).
    bool rb[UNROLL];
#pragma unroll
    for (int k = 0; k < UNROLL; ++k) {
        int r = (row0 + k) & (RR - 1);
        rb[k] = ((smask[r >> 5] >> (r & 31)) & 1u) != 0u;
    }

    int iters = (nrows - row0 + rowstride - 1) / rowstride;
    long long q0 = (long long)row0 * 256 + tid;

    f4 A[UNROLL], B[UNROLL];
    LOADV(A, q0)
    long long qprev = q0;
    bool prevA = true;
    for (int t = 1; t < iters; ++t) {
        long long qt = qprev + qstride;
        if (prevA) { LOADV(B, qt) PSTOREV(A, qprev) }
        else       { LOADV(A, qt) PSTOREV(B, qprev) }
        prevA = !prevA;
        qprev = qt;
    }
    if (prevA) { PSTOREV(A, qprev) }
    else       { PSTOREV(B, qprev) }
}

extern "C" void kernel_launch(void* const* d_in, const int* in_sizes, int n_in,
                              void* d_out, int out_size, void* d_ws, size_t ws_size,
                              hipStream_t stream) {
    const float* x  = (const float*)d_in[0];
    const int* rows = (const int*)d_in[1];
    const int* cols = (const int*)d_in[2];
    float* out      = (float*)d_out;

    const int nr = in_sizes[1];
    const int nc = in_sizes[2];

    int nrows = in_sizes[0] / CC;   // B * R = 262144
    int block = 256;
    int grid = 4096;                // 4096*4 = 16384 rows/sweep, % 1024 == 0
    if (grid * UNROLL > nrows) grid = (nrows + UNROLL - 1) / UNROLL;  // -> iters==1
    copy_mute_kernel<<<grid, block, 0, stream>>>(
        (const f4*)x, (f4*)out, rows, cols, nr, nc, nrows);
}